// Round 3
// baseline (3896.583 us; speedup 1.0000x reference)
//
#include <hip/hip_runtime.h>

#define N_NODES 20000
#define E_EDGES 160000
#define NFEAT   512
#define NHID    512
#define NCLASS  64
#define NLAYERS 4

#define SCAN_CHUNK 1024
#define NBLK 20                 // ceil(N_NODES / SCAN_CHUNK)
#define GRID 1024               // 4 blocks/CU x 256 CU -- co-resident by construction
#define TPB  256

using bf16x8 = __attribute__((ext_vector_type(8))) short;
using f32x4  = __attribute__((ext_vector_type(4))) float;
using u16x8  = __attribute__((ext_vector_type(8))) unsigned short;

__device__ __forceinline__ unsigned short f2bf(float f) {
    union { float f; unsigned int u; } v; v.f = f;
    unsigned int u = v.u + 0x7FFFu + ((v.u >> 16) & 1u);   // RNE
    return (unsigned short)(u >> 16);
}
__device__ __forceinline__ float bf2f(unsigned short h) {
    union { unsigned int u; float f; } v; v.u = ((unsigned int)h) << 16;
    return v.f;
}
__device__ __forceinline__ void gl2lds16(const void* gptr, void* lptr) {
    __builtin_amdgcn_global_load_lds(
        (const __attribute__((address_space(1))) unsigned int*)gptr,
        (__attribute__((address_space(3))) unsigned int*)lptr,
        16, 0, 0);
}

// LDS union: GEMM tiles dominate (24576 B). 24 KB/block -> LDS allows 6/CU;
// VGPR cap 128 (launch_bounds 256,4) -> 4/CU; grid 1024 = exactly 4 x 256 CU.
union SMem {
    struct { unsigned short lA[2][64 * 32]; unsigned short lB[2][128 * 32]; } g;
    struct { float tile[32][33]; int bins[NBLK]; } p;
    struct { int part[256]; int boff; } s;
};

// ---- device-scope grid barrier (all GRID blocks co-resident; G16 pattern) ----
// bar[0] = arrive count, bar[1] = generation. Agent-scope atomics: acquire
// invalidates stale L1/per-XCD-L2 lines; threadfence releases this thread's
// writes to the coherence point.
__device__ __forceinline__ void grid_sync(int* bar) {
    __threadfence();
    __syncthreads();
    if (threadIdx.x == 0) {
        const int g = __hip_atomic_load(bar + 1, __ATOMIC_RELAXED,
                                        __HIP_MEMORY_SCOPE_AGENT);
        const int v = __hip_atomic_fetch_add(bar, 1, __ATOMIC_ACQ_REL,
                                             __HIP_MEMORY_SCOPE_AGENT);
        if (v == GRID - 1) {
            __hip_atomic_store(bar, 0, __ATOMIC_RELAXED, __HIP_MEMORY_SCOPE_AGENT);
            __hip_atomic_fetch_add(bar + 1, 1, __ATOMIC_ACQ_REL,
                                   __HIP_MEMORY_SCOPE_AGENT);
        } else {
            while (__hip_atomic_load(bar + 1, __ATOMIC_ACQUIRE,
                                     __HIP_MEMORY_SCOPE_AGENT) == g)
                __builtin_amdgcn_s_sleep(8);
        }
        __threadfence();
    }
    __syncthreads();
}

// ---- GEMM phase: BK=32, dbuf + counted vmcnt, 4-chunk XOR swizzle ----------
// Rows are 64B = 4 x 16B chunks; physical chunk = logical ^ (row&3), applied
// to the GLOBAL source (gl2lds writes LDS linearly) and to the ds_read addr
// (rule 21: both sides). 8-way conflict -> ~4-way.
template <int BM, int BN, int WR, int WC, bool RELU, bool HASBIAS, bool OUTBF16>
__device__ __forceinline__ void gemm_phase(SMem* sm,
        const unsigned short* __restrict__ A, const unsigned short* __restrict__ BT,
        const float* __restrict__ bias, void* __restrict__ Cout,
        int M, int N, int K) {
    constexpr int BK  = 32;
    constexpr int R   = BM / (16 * WR);
    constexpr int C   = BN / (16 * WC);
    constexpr int RA  = (BM * BK) / (256 * 8);
    constexpr int RB  = (BN * BK) / (256 * 8);
    constexpr int LPT = RA + RB;

    const int t    = threadIdx.x;
    const int lane = t & 63;
    const int wv   = t >> 6;
    const int wr   = wv / WC;
    const int wc   = wv % WC;
    const int lm   = lane & 15;
    const int quad = lane >> 4;
    const int sw   = lm & 3;

    const int MBLK  = (M + BM - 1) / BM;
    const int NBN   = N / BN;
    const int njobs = MBLK * NBN;

    for (int j = blockIdx.x; j < njobs; j += GRID) {
        // XCD swizzle on job index (job j runs on block j%GRID -> XCD j%8):
        // same-XCD jobs share mblk -> A-slab L2 reuse.
        int mblk, nblk;
        {
            const int full = (MBLK / 8) * 8 * NBN;
            if (j < full) {
                const int g = j / (8 * NBN);
                const int l = j % (8 * NBN);
                mblk = g * 8 + (l & 7);
                nblk = l >> 3;
            } else {
                const int t2  = j - full;
                const int rem = MBLK & 7;
                mblk = (MBLK / 8) * 8 + t2 % rem;
                nblk = t2 / rem;
            }
        }
        const int m0 = mblk * BM;
        const int n0 = nblk * BN;

        f32x4 acc[R][C] = {};

        auto stage = [&](int s, int kt) {
#pragma unroll
            for (int i = 0; i < RA; ++i) {
                int idx = i * 256 + t;
                int row = idx >> 2;
                int c4  = idx & 3;
                int gr = m0 + row; if (gr >= M) gr = M - 1;
                gl2lds16(A + (size_t)gr * K + kt + ((c4 ^ (row & 3)) << 3),
                         &sm->g.lA[s][idx * 8]);
            }
#pragma unroll
            for (int i = 0; i < RB; ++i) {
                int idx = i * 256 + t;
                int row = idx >> 2;
                int c4  = idx & 3;
                gl2lds16(BT + (size_t)(n0 + row) * K + kt + ((c4 ^ (row & 3)) << 3),
                         &sm->g.lB[s][idx * 8]);
            }
        };

        stage(0, 0);
        int cur = 0;
        for (int kt = 0; kt < K; kt += BK) {
            if (kt + BK < K) {
                stage(cur ^ 1, kt + BK);
                asm volatile("s_waitcnt vmcnt(%0)" :: "i"(LPT) : "memory");
            } else {
                asm volatile("s_waitcnt vmcnt(0)" ::: "memory");
            }
            __builtin_amdgcn_sched_barrier(0);
            __builtin_amdgcn_s_barrier();

            bf16x8 af[R], bfr[C];
#pragma unroll
            for (int r = 0; r < R; ++r)
                af[r] = *(const bf16x8*)
                    &sm->g.lA[cur][(wr * R * 16 + r * 16 + lm) * BK +
                                   ((quad ^ sw) << 3)];
#pragma unroll
            for (int c = 0; c < C; ++c)
                bfr[c] = *(const bf16x8*)
                    &sm->g.lB[cur][(wc * C * 16 + c * 16 + lm) * BK +
                                   ((quad ^ sw) << 3)];
            asm volatile("s_waitcnt lgkmcnt(0)" ::: "memory");
            __builtin_amdgcn_sched_barrier(0);
#pragma unroll
            for (int r = 0; r < R; ++r)
#pragma unroll
                for (int c = 0; c < C; ++c)
                    acc[r][c] = __builtin_amdgcn_mfma_f32_16x16x32_bf16(
                        af[r], bfr[c], acc[r][c], 0, 0, 0);
            __builtin_amdgcn_sched_barrier(0);
            __builtin_amdgcn_s_barrier();
            cur ^= 1;
        }

        // epilogue: C/D layout col=lane&15, row=quad*4+reg
#pragma unroll
        for (int r = 0; r < R; ++r) {
#pragma unroll
            for (int c = 0; c < C; ++c) {
                const int colg = n0 + wc * C * 16 + c * 16 + lm;
                const float bb = HASBIAS ? bias[colg] : 0.0f;
                const int rowb = m0 + wr * R * 16 + r * 16 + quad * 4;
#pragma unroll
                for (int i = 0; i < 4; ++i) {
                    const int rr = rowb + i;
                    if (rr < M) {
                        float v = acc[r][c][i] + bb;
                        if (RELU) v = fmaxf(v, 0.0f);
                        if (OUTBF16)
                            ((unsigned short*)Cout)[(size_t)rr * N + colg] = f2bf(v);
                        else
                            ((float*)Cout)[(size_t)rr * N + colg] = v;
                    }
                }
            }
        }
    }
}

// ---- CSR-pull aggregation phase ----
__device__ __forceinline__ void agg_phase(const unsigned short* __restrict__ hW,
                                          const int* __restrict__ row_ptr,
                                          const int2* __restrict__ ew,
                                          const float* __restrict__ dinv,
                                          const float* __restrict__ bias,
                                          unsigned short* __restrict__ out) {
    const int wv   = threadIdx.x >> 6;
    const int lane = threadIdx.x & 63;
    const int njobs = (N_NODES + 3) / 4;
    for (int job = blockIdx.x; job < njobs; job += GRID) {
        int d = job * 4 + wv;
        d = __builtin_amdgcn_readfirstlane(d);
        if (d < N_NODES) {
            const int beg = __builtin_amdgcn_readfirstlane(row_ptr[d]);
            const int end = __builtin_amdgcn_readfirstlane(row_ptr[d + 1]);
            const size_t foff = (size_t)lane * 8;

            const float di = dinv[d];
            const float sl = di * di;
            u16x8 sv = *(const u16x8*)(hW + (size_t)d * NHID + foff);
            float acc[8];
#pragma unroll
            for (int i = 0; i < 8; ++i) acc[i] = bf2f(sv[i]) * sl;

            for (int j = beg; j < end; j += 8) {
                int   sK[8];
                float wK[8];
                u16x8 v[8];
#pragma unroll
                for (int k = 0; k < 8; ++k) {
                    const int jj = j + k;            // may overrun into pad (safe)
                    const int2 e = ew[jj];
                    const bool valid = jj < end;     // wave-uniform
                    sK[k] = valid ? e.x : 0;
                    wK[k] = valid ? __int_as_float(e.y) : 0.0f;
                }
#pragma unroll
                for (int k = 0; k < 8; ++k)
                    v[k] = *(const u16x8*)(hW + (size_t)sK[k] * NHID + foff);
#pragma unroll
                for (int k = 0; k < 8; ++k)
#pragma unroll
                    for (int i = 0; i < 8; ++i)
                        acc[i] += bf2f(v[k][i]) * wK[k];
            }

            const float4 b0v = *(const float4*)(bias + foff);
            const float4 b1v = *(const float4*)(bias + foff + 4);
            u16x8 r;
            r[0] = f2bf(fmaxf(acc[0] + b0v.x, 0.0f));
            r[1] = f2bf(fmaxf(acc[1] + b0v.y, 0.0f));
            r[2] = f2bf(fmaxf(acc[2] + b0v.z, 0.0f));
            r[3] = f2bf(fmaxf(acc[3] + b0v.w, 0.0f));
            r[4] = f2bf(fmaxf(acc[4] + b1v.x, 0.0f));
            r[5] = f2bf(fmaxf(acc[5] + b1v.y, 0.0f));
            r[6] = f2bf(fmaxf(acc[6] + b1v.z, 0.0f));
            r[7] = f2bf(fmaxf(acc[7] + b1v.w, 0.0f));
            *(u16x8*)(out + (size_t)d * NHID + foff) = r;
        }
    }
}

// ================= the whole network as ONE persistent kernel ===============
__global__ __launch_bounds__(256, 4) void mega(
        const int* __restrict__ src, const int* __restrict__ dst,
        int* __restrict__ counts, int* __restrict__ bsums, int* __restrict__ bar,
        const float* __restrict__ W_enc, const float* __restrict__ W_convs,
        const float* __restrict__ W_dec,
        unsigned short* __restrict__ WencT, unsigned short* __restrict__ WcvT,
        unsigned short* __restrict__ WdecT,
        const float* __restrict__ x, unsigned short* __restrict__ Xbf,
        int* __restrict__ row_ptr, int* __restrict__ cursor,
        float* __restrict__ dinv, int2* __restrict__ ew,
        const float* __restrict__ b_enc, const float* __restrict__ b_convs,
        const float* __restrict__ b_dec,
        unsigned short* __restrict__ B1, unsigned short* __restrict__ B2,
        float* __restrict__ out) {
    __shared__ SMem sm;
    const int t = threadIdx.x, bid = blockIdx.x;

    // ---- P0a: edge counting (single pass: GRID*TPB = 262144 > E_EDGES) ----
    {
        if (t < NBLK) sm.p.bins[t] = 0;
        __syncthreads();
        const int e = bid * TPB + t;
        if (e < E_EDGES) {
            const int d = dst[e];
            atomicAdd(&counts[d], 1);
            atomicAdd(&sm.p.bins[d >> 10], 1);
        }
        __syncthreads();
        if (t < NBLK && sm.p.bins[t]) atomicAdd(&bsums[t], sm.p.bins[t]);
    }

    // ---- P0b: weight transposes (6 matrices x 256 tile-jobs) ----
    for (int job = bid; job < 6 * 256; job += GRID) {
        const int id  = job >> 8;
        const int rem = job & 255;
        const int n0  = (rem & 15) * 32;
        const int k0  = (rem >> 4) * 32;
        const float* W; unsigned short* WT; int Nn;
        const int K = 512;
        if (id == 0)            { W = W_enc; WT = WencT; Nn = NHID; }
        else if (id <= NLAYERS) { W = W_convs + (size_t)(id - 1) * NHID * NHID;
                                  WT = WcvT  + (size_t)(id - 1) * NHID * NHID; Nn = NHID; }
        else                    { W = W_dec; WT = WdecT; Nn = NCLASS; }
        if (n0 < Nn) {                      // block-uniform guard
            const int tx = t & 31, ty = t >> 5;
#pragma unroll
            for (int i = 0; i < 32; i += 8)
                sm.p.tile[ty + i][tx] = W[(size_t)(k0 + ty + i) * Nn + n0 + tx];
            __syncthreads();
#pragma unroll
            for (int i = 0; i < 32; i += 8)
                WT[(size_t)(n0 + ty + i) * K + k0 + tx] = f2bf(sm.p.tile[tx][ty + i]);
            __syncthreads();                // protect tile for next job
        }
    }

    // ---- P0c: x fp32 -> bf16 (into B2 scratch) ----
    for (int c = bid * TPB + t; c < (N_NODES * NFEAT) / 8; c += GRID * TPB) {
        const size_t base = (size_t)c * 8;
        const float4 f0 = *(const float4*)(x + base);
        const float4 f1 = *(const float4*)(x + base + 4);
        u16x8 pk;
        pk[0] = f2bf(f0.x); pk[1] = f2bf(f0.y);
        pk[2] = f2bf(f0.z); pk[3] = f2bf(f0.w);
        pk[4] = f2bf(f1.x); pk[5] = f2bf(f1.y);
        pk[6] = f2bf(f1.z); pk[7] = f2bf(f1.w);
        *(u16x8*)(Xbf + base) = pk;
    }
    grid_sync(bar);   // 1

    // ---- P1: row_ptr + cursor + dinv (blocks 0..19) ----
    if (bid < NBLK) {
        if (t < 64) {
            int v = (t < NBLK && t < bid) ? bsums[t] : 0;
            for (int off = 32; off > 0; off >>= 1) v += __shfl_xor(v, off, 64);
            if (t == 0) sm.s.boff = v;
        }
        const int base = bid * SCAN_CHUNK + t * 4;
        int c[4], s = 0;
        for (int i = 0; i < 4; ++i) {
            int idx = base + i;
            c[i] = (idx < N_NODES) ? counts[idx] : 0;
            s += c[i];
        }
        sm.s.part[t] = s;
        __syncthreads();
        for (int off = 1; off < 256; off <<= 1) {
            int v = (t >= off) ? sm.s.part[t - off] : 0;
            __syncthreads();
            sm.s.part[t] += v;
            __syncthreads();
        }
        int run = sm.s.boff + ((t == 0) ? 0 : sm.s.part[t - 1]);
        for (int i = 0; i < 4; ++i) {
            int idx = base + i;
            if (idx < N_NODES) {
                row_ptr[idx] = run;
                cursor[idx]  = run;
                dinv[idx]    = rsqrtf((float)c[i] + 1.0f);
                run += c[i];
            }
        }
        if (bid == 0 && t == 0) row_ptr[N_NODES] = E_EDGES;
    }
    grid_sync(bar);   // 2

    // ---- P2: csr_fill (single pass) ----
    {
        const int e = bid * TPB + t;
        if (e < E_EDGES) {
            int s = src[e], d = dst[e];
            int pos = atomicAdd(&cursor[d], 1);
            ew[pos] = make_int2(s, __float_as_int(dinv[s] * dinv[d]));
        }
        if (e < 8) ew[E_EDGES + e] = make_int2(0, 0);
    }
    grid_sync(bar);   // 3

    // ---- P3: encoder GEMM ----
    gemm_phase<64, 128, 2, 2, true, true, true>(&sm, Xbf, WencT, b_enc, B1,
                                                N_NODES, NHID, NFEAT);
    grid_sync(bar);   // 4

    // ---- P4..P11: conv layers ----
    for (int L = 0; L < NLAYERS; ++L) {
        gemm_phase<64, 128, 2, 2, false, false, true>(
            &sm, B1, WcvT + (size_t)L * NHID * NHID, nullptr, B2,
            N_NODES, NHID, NHID);
        grid_sync(bar);
        agg_phase(B2, row_ptr, ew, dinv, b_convs + (size_t)L * NHID, B1);
        grid_sync(bar);
    }

    // ---- P12: decoder GEMM ----
    gemm_phase<64, 64, 2, 2, false, true, false>(&sm, B1, WdecT, b_dec, out,
                                                 N_NODES, NCLASS, NHID);
}

// ================= launch =================
extern "C" void kernel_launch(void* const* d_in, const int* in_sizes, int n_in,
                              void* d_out, int out_size, void* d_ws, size_t ws_size,
                              hipStream_t stream) {
    const float* x       = (const float*)d_in[0];
    const int*   ei      = (const int*)d_in[1];
    const float* W_enc   = (const float*)d_in[2];
    const float* b_enc   = (const float*)d_in[3];
    const float* W_convs = (const float*)d_in[4];
    const float* b_convs = (const float*)d_in[5];
    const float* W_dec   = (const float*)d_in[6];
    const float* b_dec   = (const float*)d_in[7];
    float* out = (float*)d_out;

    const int* src = ei;
    const int* dst = ei + E_EDGES;

    char* ws = (char*)d_ws;
    auto alloc = [&](size_t bytes) {
        char* p = ws;
        ws += (bytes + 255) / 256 * 256;
        return p;
    };
    float* dinv     = (float*)alloc(N_NODES * 4);
    int*   counts   = (int*)  alloc((N_NODES + NBLK + 2) * 4);  // + bsums + bar
    int*   bsums    = counts + N_NODES;
    int*   bar      = bsums + NBLK;
    int*   row_ptr  = (int*)  alloc((N_NODES + 1) * 4);
    int*   cursor   = (int*)  alloc(N_NODES * 4);
    int2*  ew       = (int2*) alloc((E_EDGES + 8) * 8);
    unsigned short* WencT = (unsigned short*)alloc((size_t)NFEAT * NHID * 2);
    unsigned short* WcvT  = (unsigned short*)alloc((size_t)NLAYERS * NHID * NHID * 2);
    unsigned short* WdecT = (unsigned short*)alloc((size_t)NHID * NCLASS * 2);
    unsigned short* B1    = (unsigned short*)alloc((size_t)N_NODES * NHID * 2);
    unsigned short* B2    = (unsigned short*)alloc((size_t)N_NODES * NHID * 2);
    unsigned short* Xbf   = B2;   // x-bf16 scratch: dead once encoder GEMM ran

    hipMemsetAsync(counts, 0, (N_NODES + NBLK + 2) * sizeof(int), stream);
    mega<<<GRID, TPB, 0, stream>>>(src, dst, counts, bsums, bar,
                                   W_enc, W_convs, W_dec, WencT, WcvT, WdecT,
                                   x, Xbf, row_ptr, cursor, dinv, ew,
                                   b_enc, b_convs, b_dec, B1, B2, out);
}

// Round 5
// 407.832 us; speedup vs baseline: 9.5544x; 9.5544x over previous
//
#include <hip/hip_runtime.h>

#define N_NODES 20000
#define E_EDGES 160000
#define NFEAT   512
#define NHID    512
#define NCLASS  64
#define NLAYERS 4

#define SCAN_CHUNK 1024
#define NBLK ((N_NODES + SCAN_CHUNK - 1) / SCAN_CHUNK)   // 20
#define CNT_BLOCKS ((E_EDGES + 255) / 256)               // 625
#define CVT_BLOCKS ((N_NODES * NFEAT) / 2048)            // 5000 (8 floats/thread)

using bf16x8 = __attribute__((ext_vector_type(8))) short;          // MFMA A/B frag
using f32x4  = __attribute__((ext_vector_type(4))) float;          // MFMA C/D frag
using u16x8  = __attribute__((ext_vector_type(8))) unsigned short; // 16B bf16 vector

__device__ __forceinline__ unsigned short f2bf(float f) {
    union { float f; unsigned int u; } v; v.f = f;
    unsigned int u = v.u + 0x7FFFu + ((v.u >> 16) & 1u);   // RNE
    return (unsigned short)(u >> 16);
}
__device__ __forceinline__ float bf2f(unsigned short h) {
    union { unsigned int u; float f; } v; v.u = ((unsigned int)h) << 16;
    return v.f;
}
__device__ __forceinline__ void gl2lds16(const void* gptr, void* lptr) {
    __builtin_amdgcn_global_load_lds(
        (const __attribute__((address_space(1))) unsigned int*)gptr,
        (__attribute__((address_space(3))) unsigned int*)lptr,
        16, 0, 0);
}

// ==== fused prep: edge counting + weight transposes + x fp32->bf16 convert ====
__global__ __launch_bounds__(256) void prep_all(const int* __restrict__ dst,
                                                int* __restrict__ counts,
                                                int* __restrict__ bsums,
                                                const float* __restrict__ W_enc,
                                                const float* __restrict__ W_convs,
                                                const float* __restrict__ W_dec,
                                                unsigned short* __restrict__ WencT,
                                                unsigned short* __restrict__ WcvT,
                                                unsigned short* __restrict__ WdecT,
                                                const float* __restrict__ x,
                                                unsigned short* __restrict__ Xbf) {
    __shared__ int bins[NBLK];
    __shared__ float tile[32][33];
    const int b = blockIdx.x, t = threadIdx.x;

    if (b < CNT_BLOCKS) {
        if (t < NBLK) bins[t] = 0;
        __syncthreads();
        const int e = b * 256 + t;
        if (e < E_EDGES) {
            const int d = dst[e];
            atomicAdd(&counts[d], 1);
            atomicAdd(&bins[d >> 10], 1);         // SCAN_CHUNK = 1024
        }
        __syncthreads();
        if (t < NBLK && bins[t]) atomicAdd(&bsums[t], bins[t]);
        return;
    }

    if (b >= CNT_BLOCKS + 6 * 256) {
        // ---- convert x -> bf16 (into B2 scratch; dead after encoder GEMM) ----
        const int cid = b - CNT_BLOCKS - 6 * 256;
        const size_t base = (size_t)cid * 2048 + (size_t)t * 8;
        const float4 f0 = *(const float4*)(x + base);
        const float4 f1 = *(const float4*)(x + base + 4);
        u16x8 pk;
        pk[0] = f2bf(f0.x); pk[1] = f2bf(f0.y);
        pk[2] = f2bf(f0.z); pk[3] = f2bf(f0.w);
        pk[4] = f2bf(f1.x); pk[5] = f2bf(f1.y);
        pk[6] = f2bf(f1.z); pk[7] = f2bf(f1.w);
        *(u16x8*)(Xbf + base) = pk;
        return;
    }

    // ---- transpose role ----
    const int bid = b - CNT_BLOCKS;
    const int id  = bid >> 8;            // matrix 0..5
    const int rem = bid & 255;
    const int n0  = (rem & 15) * 32;
    const int k0  = (rem >> 4) * 32;
    const float* W; unsigned short* WT; int N;
    const int K = 512;
    if (id == 0)            { W = W_enc; WT = WencT; N = NHID; }
    else if (id <= NLAYERS) { W = W_convs + (size_t)(id - 1) * NHID * NHID;
                              WT = WcvT  + (size_t)(id - 1) * NHID * NHID; N = NHID; }
    else                    { W = W_dec; WT = WdecT; N = NCLASS; }
    if (n0 >= N) return;
    const int tx = t & 31, ty = t >> 5;
#pragma unroll
    for (int i = 0; i < 32; i += 8)
        tile[ty + i][tx] = W[(size_t)(k0 + ty + i) * N + n0 + tx];
    __syncthreads();
#pragma unroll
    for (int i = 0; i < 32; i += 8)
        WT[(size_t)(n0 + ty + i) * K + k0 + tx] = f2bf(tile[tx][ty + i]);
}

// row_ptr + cursor + dinv in one pass; bsums-prefix fused in (wave 0 reduces)
__global__ __launch_bounds__(256) void write_rowptr(const int* __restrict__ counts,
                                                    const int* __restrict__ bsums,
                                                    int* __restrict__ row_ptr,
                                                    int* __restrict__ cursor,
                                                    float* __restrict__ dinv) {
    __shared__ int part[256];
    __shared__ int boff_s;
    const int b = blockIdx.x, t = threadIdx.x;

    if (t < 64) {               // wave 0: boff_s = sum of bsums[0..b-1]
        int v = (t < NBLK && t < b) ? bsums[t] : 0;
        for (int off = 32; off > 0; off >>= 1) v += __shfl_xor(v, off, 64);
        if (t == 0) boff_s = v;
    }

    const int base = b * SCAN_CHUNK + t * 4;
    int c[4], s = 0;
    for (int i = 0; i < 4; ++i) {
        int idx = base + i;
        c[i] = (idx < N_NODES) ? counts[idx] : 0;
        s += c[i];
    }
    part[t] = s;
    __syncthreads();
    for (int off = 1; off < 256; off <<= 1) {
        int v = (t >= off) ? part[t - off] : 0;
        __syncthreads();
        part[t] += v;
        __syncthreads();
    }
    int run = boff_s + ((t == 0) ? 0 : part[t - 1]);
    for (int i = 0; i < 4; ++i) {
        int idx = base + i;
        if (idx < N_NODES) {
            row_ptr[idx] = run;
            cursor[idx]  = run;
            dinv[idx]    = rsqrtf((float)c[i] + 1.0f);
            run += c[i];
        }
    }
    if (b == 0 && t == 0) row_ptr[N_NODES] = E_EDGES;
}

// fill packed (col, wgt) pairs; pad 8 entries past E with {node 0, weight 0}
__global__ __launch_bounds__(256) void csr_fill(const int* __restrict__ src,
                                                const int* __restrict__ dst,
                                                const float* __restrict__ dinv,
                                                int* __restrict__ cursor,
                                                int2* __restrict__ ew) {
    int e = blockIdx.x * 256 + threadIdx.x;
    if (e < E_EDGES) {
        int s = src[e], d = dst[e];
        int pos = atomicAdd(&cursor[d], 1);
        ew[pos] = make_int2(s, __float_as_int(dinv[s] * dinv[d]));
    }
    if (e < 8) ew[E_EDGES + e] = make_int2(0, 0);
}

// ========= bf16 MFMA GEMM, B-resident-in-LDS, BARRIER-FREE K-loop ==========
// C[M,N] = A[M,K] @ B[K,N]; A bf16 row-major, BT = B^T bf16 [N][K], K=512.
// The entire B^T panel for this block's BN=64 columns (64 x 512 x 2B = 64 KB)
// is staged into LDS ONCE (one __syncthreads). The K-loop then has NO
// barriers: A-fragments load straight from global into VGPRs (MFMA A layout
// row=lm, k=quad*8 exactly matches row-major A), 1-deep register prefetch,
// B-frags from read-only LDS. Waves slip independently -> no convoy stalls.
// LDS swizzle (rule 21, both sides): B^T row = 1024 B = 64 x 16B chunks;
// physical chunk low-3 = logical ^ (row&7). Applied to the GLOBAL source at
// staging (gl2lds writes LDS linearly, m173) and to the ds_read address.
// 16 lanes of a quad read 16 consecutive rows -> 8 bank-groups x 2-way = free.
// XCD swizzle: the NBN n-blocks of one m-slab land on one XCD -> A-slab read
// from HBM once, 7x from that XCD's L2.
template <int R, int BN, bool RELU, bool HASBIAS, bool OUTBF16>
__global__ __launch_bounds__(256) void gemm_bres(const unsigned short* __restrict__ A,
                                                 const unsigned short* __restrict__ BT,
                                                 const float* __restrict__ bias,
                                                 void* __restrict__ Cout,
                                                 int M, int N) {
    constexpr int K  = 512;
    constexpr int BM = 4 * R * 16;          // 4 waves x R frags x 16 rows
    constexpr int C  = BN / 16;             // n-frags per wave (all waves same n)
    __shared__ unsigned short lB[BN * K];   // 64 KB for BN=64

    const int t    = threadIdx.x;
    const int lane = t & 63;
    const int wv   = t >> 6;
    const int lm   = lane & 15;
    const int q    = lane >> 4;

    const int MBLK = (M + BM - 1) / BM;
    const int NBN  = N / BN;
    int mblk, nblk;
    {
        const int i    = blockIdx.x;
        const int full = (MBLK / 8) * 8 * NBN;
        if (i < full) {
            const int g = i / (8 * NBN);
            const int l = i % (8 * NBN);
            mblk = g * 8 + (l & 7);
            nblk = l >> 3;
        } else {
            const int t2  = i - full;
            const int rem = MBLK & 7;
            mblk = (MBLK / 8) * 8 + t2 % rem;
            nblk = t2 / rem;
        }
    }
    const int m0 = mblk * BM;
    const int n0 = nblk * BN;

    // ---- stage the whole B^T panel (BN x 512), swizzled source ----
#pragma unroll
    for (int i = 0; i < (BN * 64) / 256; ++i) {      // 16B chunks
        const int idx = i * 256 + t;
        const int row = idx >> 6;                    // 64 chunks per row
        const int c64 = idx & 63;
        const int g   = (c64 & ~7) | ((c64 & 7) ^ (row & 7));
        gl2lds16(BT + (size_t)(n0 + row) * K + g * 8, &lB[idx * 8]);
    }
    __syncthreads();                                 // only barrier in kernel

    // ---- per-lane A row pointers (clamped for the ragged last m-slab) ----
    const unsigned short* ap[R];
#pragma unroll
    for (int r = 0; r < R; ++r) {
        int gr = m0 + wv * R * 16 + r * 16 + lm;
        if (gr >= M) gr = M - 1;
        ap[r] = A + (size_t)gr * K + q * 8;
    }

    f32x4 acc[R][C] = {};
    bf16x8 aC[R], aN[R];
#pragma unroll
    for (int r = 0; r < R; ++r) aC[r] = *(const bf16x8*)ap[r];

    for (int kt = 0; kt < K; kt += 32) {
        if (kt + 32 < K) {
#pragma unroll
            for (int r = 0; r < R; ++r)
                aN[r] = *(const bf16x8*)(ap[r] + kt + 32);   // 1-deep prefetch
        }
        bf16x8 bf[C];
        const int cb = kt >> 3;                      // chunk base (mult of 4)
#pragma unroll
        for (int c = 0; c < C; ++c) {
            const int row  = c * 16 + lm;
            const int c64  = cb + q;
            const int phys = (c64 & ~7) | ((c64 & 7) ^ (row & 7));
            bf[c] = *(const bf16x8*)&lB[row * K + phys * 8];
        }
#pragma unroll
        for (int r = 0; r < R; ++r)
#pragma unroll
            for (int c = 0; c < C; ++c)
                acc[r][c] = __builtin_amdgcn_mfma_f32_16x16x32_bf16(
                    aC[r], bf[c], acc[r][c], 0, 0, 0);
#pragma unroll
        for (int r = 0; r < R; ++r) aC[r] = aN[r];
    }

    // epilogue: C/D layout col=lane&15, row=quad*4+reg
#pragma unroll
    for (int r = 0; r < R; ++r) {
#pragma unroll
        for (int c = 0; c < C; ++c) {
            const int colg = n0 + c * 16 + lm;
            const float bb = HASBIAS ? bias[colg] : 0.0f;
            const int rowb = m0 + wv * R * 16 + r * 16 + q * 4;
#pragma unroll
            for (int i = 0; i < 4; ++i) {
                const int rr = rowb + i;
                if (rr < M) {
                    float v = acc[r][c][i] + bb;
                    if (RELU) v = fmaxf(v, 0.0f);
                    if (OUTBF16)
                        ((unsigned short*)Cout)[(size_t)rr * N + colg] = f2bf(v);
                    else
                        ((float*)Cout)[(size_t)rr * N + colg] = v;
                }
            }
        }
    }
}

// ================= CSR-pull aggregation =================
__global__ __launch_bounds__(256) void gcn_aggregate(const unsigned short* __restrict__ hW,
                                                     const int* __restrict__ row_ptr,
                                                     const int2* __restrict__ ew,
                                                     const float* __restrict__ dinv,
                                                     const float* __restrict__ bias,
                                                     unsigned short* __restrict__ out) {
    const int wv   = threadIdx.x >> 6;
    const int lane = threadIdx.x & 63;
    int d = blockIdx.x * 4 + wv;
    d = __builtin_amdgcn_readfirstlane(d);
    if (d >= N_NODES) return;
    const int beg = __builtin_amdgcn_readfirstlane(row_ptr[d]);
    const int end = __builtin_amdgcn_readfirstlane(row_ptr[d + 1]);
    const size_t foff = (size_t)lane * 8;

    const float di = dinv[d];
    const float sl = di * di;
    u16x8 sv = *(const u16x8*)(hW + (size_t)d * NHID + foff);
    float acc[8];
#pragma unroll
    for (int i = 0; i < 8; ++i) acc[i] = bf2f(sv[i]) * sl;

    for (int j = beg; j < end; j += 8) {
        int   sK[8];
        float wK[8];
        u16x8 v[8];
#pragma unroll
        for (int k = 0; k < 8; ++k) {
            const int jj = j + k;            // may overrun into pad (safe)
            const int2 e = ew[jj];
            const bool valid = jj < end;     // wave-uniform
            sK[k] = valid ? e.x : 0;
            wK[k] = valid ? __int_as_float(e.y) : 0.0f;
        }
#pragma unroll
        for (int k = 0; k < 8; ++k)
            v[k] = *(const u16x8*)(hW + (size_t)sK[k] * NHID + foff);
#pragma unroll
        for (int k = 0; k < 8; ++k)
#pragma unroll
            for (int i = 0; i < 8; ++i)
                acc[i] += bf2f(v[k][i]) * wK[k];
    }

    const float4 b0v = *(const float4*)(bias + foff);
    const float4 b1v = *(const float4*)(bias + foff + 4);
    u16x8 r;
    r[0] = f2bf(fmaxf(acc[0] + b0v.x, 0.0f));
    r[1] = f2bf(fmaxf(acc[1] + b0v.y, 0.0f));
    r[2] = f2bf(fmaxf(acc[2] + b0v.z, 0.0f));
    r[3] = f2bf(fmaxf(acc[3] + b0v.w, 0.0f));
    r[4] = f2bf(fmaxf(acc[4] + b1v.x, 0.0f));
    r[5] = f2bf(fmaxf(acc[5] + b1v.y, 0.0f));
    r[6] = f2bf(fmaxf(acc[6] + b1v.z, 0.0f));
    r[7] = f2bf(fmaxf(acc[7] + b1v.w, 0.0f));
    *(u16x8*)(out + (size_t)d * NHID + foff) = r;
}

// ================= launch =================
extern "C" void kernel_launch(void* const* d_in, const int* in_sizes, int n_in,
                              void* d_out, int out_size, void* d_ws, size_t ws_size,
                              hipStream_t stream) {
    const float* x       = (const float*)d_in[0];
    const int*   ei      = (const int*)d_in[1];
    const float* W_enc   = (const float*)d_in[2];
    const float* b_enc   = (const float*)d_in[3];
    const float* W_convs = (const float*)d_in[4];
    const float* b_convs = (const float*)d_in[5];
    const float* W_dec   = (const float*)d_in[6];
    const float* b_dec   = (const float*)d_in[7];
    float* out = (float*)d_out;

    const int* src = ei;
    const int* dst = ei + E_EDGES;

    char* ws = (char*)d_ws;
    auto alloc = [&](size_t bytes) {
        char* p = ws;
        ws += (bytes + 255) / 256 * 256;
        return p;
    };
    float* dinv     = (float*)alloc(N_NODES * 4);
    int*   counts   = (int*)  alloc((N_NODES + NBLK) * 4);   // bsums adjacent
    int*   bsums    = counts + N_NODES;
    int*   row_ptr  = (int*)  alloc((N_NODES + 1) * 4);
    int*   cursor   = (int*)  alloc(N_NODES * 4);
    int2*  ew       = (int2*) alloc((E_EDGES + 8) * 8);
    unsigned short* WencT = (unsigned short*)alloc((size_t)NFEAT * NHID * 2);
    unsigned short* WcvT  = (unsigned short*)alloc((size_t)NLAYERS * NHID * NHID * 2);
    unsigned short* WdecT = (unsigned short*)alloc((size_t)NHID * NCLASS * 2);
    unsigned short* B1    = (unsigned short*)alloc((size_t)N_NODES * NHID * 2);
    unsigned short* B2    = (unsigned short*)alloc((size_t)N_NODES * NHID * 2);
    unsigned short* Xbf   = B2;   // x-bf16 scratch: dead once encoder GEMM ran

    // ---- CSR build + weight conversion + x conversion (fused) ----
    hipMemsetAsync(counts, 0, (N_NODES + NBLK) * sizeof(int), stream);
    prep_all<<<CNT_BLOCKS + 6 * 256 + CVT_BLOCKS, 256, 0, stream>>>(
        dst, counts, bsums, W_enc, W_convs, W_dec, WencT, WcvT, WdecT, x, Xbf);
    write_rowptr<<<NBLK, 256, 0, stream>>>(counts, bsums, row_ptr, cursor, dinv);
    csr_fill<<<(E_EDGES + 255) / 256, 256, 0, stream>>>(src, dst, dinv, cursor, ew);

    // BM=256 (R=4): MBLK=79; BN=64: NBN=8 for hidden, 1 for classes
    const int MBLK256 = (N_NODES + 255) / 256;   // 79
    const int MBLK128 = (N_NODES + 127) / 128;   // 157

    // ---- encoder: bf16 x from prep ----
    gemm_bres<4, 64, true, true, true>
        <<<MBLK256 * (NHID / 64), 256, 0, stream>>>(
        Xbf, WencT, b_enc, B1, N_NODES, NHID);

    // ---- conv layers ----
    for (int L = 0; L < NLAYERS; ++L) {
        gemm_bres<4, 64, false, false, true>
            <<<MBLK256 * (NHID / 64), 256, 0, stream>>>(
            B1, WcvT + (size_t)L * NHID * NHID, nullptr, B2, N_NODES, NHID);
        gcn_aggregate<<<(N_NODES + 3) / 4, 256, 0, stream>>>(
            B2, row_ptr, ew, dinv, b_convs + (size_t)L * NHID, B1);
    }

    // ---- decoder: R=2 (BM=128) for parallelism, single n-block ----
    gemm_bres<2, 64, false, true, false>
        <<<MBLK128 * (NCLASS / 64), 256, 0, stream>>>(
        B1, WdecT, b_dec, out, N_NODES, NCLASS);
}

// Round 6
// 397.800 us; speedup vs baseline: 9.7953x; 1.0252x over previous
//
#include <hip/hip_runtime.h>

#define N_NODES 20000
#define E_EDGES 160000
#define NFEAT   512
#define NHID    512
#define NCLASS  64
#define NLAYERS 4

#define SCAN_CHUNK 1024
#define NBLK ((N_NODES + SCAN_CHUNK - 1) / SCAN_CHUNK)   // 20
#define CNT_BLOCKS ((E_EDGES + 255) / 256)               // 625
#define CVT_BLOCKS ((N_NODES * NFEAT) / 2048)            // 5000 (8 floats/thread)

using bf16x8 = __attribute__((ext_vector_type(8))) short;          // MFMA A/B frag
using f32x4  = __attribute__((ext_vector_type(4))) float;          // MFMA C/D frag
using u16x8  = __attribute__((ext_vector_type(8))) unsigned short; // 16B bf16 vector

__device__ __forceinline__ unsigned short f2bf(float f) {
    union { float f; unsigned int u; } v; v.f = f;
    unsigned int u = v.u + 0x7FFFu + ((v.u >> 16) & 1u);   // RNE
    return (unsigned short)(u >> 16);
}
__device__ __forceinline__ float bf2f(unsigned short h) {
    union { unsigned int u; float f; } v; v.u = ((unsigned int)h) << 16;
    return v.f;
}
__device__ __forceinline__ void gl2lds16(const void* gptr, void* lptr) {
    __builtin_amdgcn_global_load_lds(
        (const __attribute__((address_space(1))) unsigned int*)gptr,
        (__attribute__((address_space(3))) unsigned int*)lptr,
        16, 0, 0);
}

// ==== fused prep: edge counting + weight transposes + x fp32->bf16 convert ====
__global__ __launch_bounds__(256) void prep_all(const int* __restrict__ dst,
                                                int* __restrict__ counts,
                                                int* __restrict__ bsums,
                                                const float* __restrict__ W_enc,
                                                const float* __restrict__ W_convs,
                                                const float* __restrict__ W_dec,
                                                unsigned short* __restrict__ WencT,
                                                unsigned short* __restrict__ WcvT,
                                                unsigned short* __restrict__ WdecT,
                                                const float* __restrict__ x,
                                                unsigned short* __restrict__ Xbf) {
    __shared__ int bins[NBLK];
    __shared__ float tile[32][33];
    const int b = blockIdx.x, t = threadIdx.x;

    if (b < CNT_BLOCKS) {
        if (t < NBLK) bins[t] = 0;
        __syncthreads();
        const int e = b * 256 + t;
        if (e < E_EDGES) {
            const int d = dst[e];
            atomicAdd(&counts[d], 1);
            atomicAdd(&bins[d >> 10], 1);         // SCAN_CHUNK = 1024
        }
        __syncthreads();
        if (t < NBLK && bins[t]) atomicAdd(&bsums[t], bins[t]);
        return;
    }

    if (b >= CNT_BLOCKS + 6 * 256) {
        // ---- convert x -> bf16 (into B2 scratch; dead after encoder GEMM) ----
        const int cid = b - CNT_BLOCKS - 6 * 256;
        const size_t base = (size_t)cid * 2048 + (size_t)t * 8;
        const float4 f0 = *(const float4*)(x + base);
        const float4 f1 = *(const float4*)(x + base + 4);
        u16x8 pk;
        pk[0] = f2bf(f0.x); pk[1] = f2bf(f0.y);
        pk[2] = f2bf(f0.z); pk[3] = f2bf(f0.w);
        pk[4] = f2bf(f1.x); pk[5] = f2bf(f1.y);
        pk[6] = f2bf(f1.z); pk[7] = f2bf(f1.w);
        *(u16x8*)(Xbf + base) = pk;
        return;
    }

    // ---- transpose role ----
    const int bid = b - CNT_BLOCKS;
    const int id  = bid >> 8;            // matrix 0..5
    const int rem = bid & 255;
    const int n0  = (rem & 15) * 32;
    const int k0  = (rem >> 4) * 32;
    const float* W; unsigned short* WT; int N;
    const int K = 512;
    if (id == 0)            { W = W_enc; WT = WencT; N = NHID; }
    else if (id <= NLAYERS) { W = W_convs + (size_t)(id - 1) * NHID * NHID;
                              WT = WcvT  + (size_t)(id - 1) * NHID * NHID; N = NHID; }
    else                    { W = W_dec; WT = WdecT; N = NCLASS; }
    if (n0 >= N) return;
    const int tx = t & 31, ty = t >> 5;
#pragma unroll
    for (int i = 0; i < 32; i += 8)
        tile[ty + i][tx] = W[(size_t)(k0 + ty + i) * N + n0 + tx];
    __syncthreads();
#pragma unroll
    for (int i = 0; i < 32; i += 8)
        WT[(size_t)(n0 + ty + i) * K + k0 + tx] = f2bf(tile[tx][ty + i]);
}

// row_ptr + cursor + dinv in one pass; bsums-prefix fused in (wave 0 reduces)
__global__ __launch_bounds__(256) void write_rowptr(const int* __restrict__ counts,
                                                    const int* __restrict__ bsums,
                                                    int* __restrict__ row_ptr,
                                                    int* __restrict__ cursor,
                                                    float* __restrict__ dinv) {
    __shared__ int part[256];
    __shared__ int boff_s;
    const int b = blockIdx.x, t = threadIdx.x;

    if (t < 64) {               // wave 0: boff_s = sum of bsums[0..b-1]
        int v = (t < NBLK && t < b) ? bsums[t] : 0;
        for (int off = 32; off > 0; off >>= 1) v += __shfl_xor(v, off, 64);
        if (t == 0) boff_s = v;
    }

    const int base = b * SCAN_CHUNK + t * 4;
    int c[4], s = 0;
    for (int i = 0; i < 4; ++i) {
        int idx = base + i;
        c[i] = (idx < N_NODES) ? counts[idx] : 0;
        s += c[i];
    }
    part[t] = s;
    __syncthreads();
    for (int off = 1; off < 256; off <<= 1) {
        int v = (t >= off) ? part[t - off] : 0;
        __syncthreads();
        part[t] += v;
        __syncthreads();
    }
    int run = boff_s + ((t == 0) ? 0 : part[t - 1]);
    for (int i = 0; i < 4; ++i) {
        int idx = base + i;
        if (idx < N_NODES) {
            row_ptr[idx] = run;
            cursor[idx]  = run;
            dinv[idx]    = rsqrtf((float)c[i] + 1.0f);
            run += c[i];
        }
    }
    if (b == 0 && t == 0) row_ptr[N_NODES] = E_EDGES;
}

// fill packed (col, wgt) pairs; pad 8 entries past E with {node 0, weight 0}
__global__ __launch_bounds__(256) void csr_fill(const int* __restrict__ src,
                                                const int* __restrict__ dst,
                                                const float* __restrict__ dinv,
                                                int* __restrict__ cursor,
                                                int2* __restrict__ ew) {
    int e = blockIdx.x * 256 + threadIdx.x;
    if (e < E_EDGES) {
        int s = src[e], d = dst[e];
        int pos = atomicAdd(&cursor[d], 1);
        ew[pos] = make_int2(s, __float_as_int(dinv[s] * dinv[d]));
    }
    if (e < 8) ew[E_EDGES + e] = make_int2(0, 0);
}

// ===== bf16 MFMA GEMM, B-half-panel-resident, barrier-free K-loop ==========
// C[M,N] = A[M,K] @ B[K,N]; A bf16 row-major, BT = B^T bf16 [N][K], K=512.
// R5 post-mortem: 64KB panel -> 2 blocks/CU -> 2 waves/SIMD -> latency-bound
// (MfmaUtil 8%, occupancy 12%). Fix: stage B^T in TWO K-halves of 32KB each
// (64 x 256 x 2B). LDS 32KB -> 5 blocks/CU; launch_bounds(256,5) caps VGPR
// at ~102 (est ~90) -> 20 waves/CU = 5 waves/SIMD. BM=128 -> grid 157x8 =
// 1256 jobs ~= 1280 resident slots -> SINGLE dispatch round (no idle tail
// round). Inner 8-step loop per half is barrier-free: A-frags straight from
// global (layout row=lm, k=q*8 matches row-major A), 1-deep prefetch; B-frags
// from read-only LDS. Only 3 __syncthreads per block (stage/reload).
// LDS swizzle (rule 21, both sides): half-row = 512B = 32 x 16B chunks;
// physical chunk = (c32&~7) | ((c32&7) ^ (row&7)), applied at the GLOBAL
// source (gl2lds writes LDS linearly, m173) and at the ds_read address.
// 16 lanes (lm 0-15) hit 8 bank-groups x 2-way = free.
// XCD swizzle: the 8 n-blocks of one m-slab land on one XCD -> A-slab read
// from HBM once, 7x from that XCD's L2.
template <int R, bool RELU, bool HASBIAS, bool OUTBF16>
__global__ __launch_bounds__(256, 5) void gemm_bres(const unsigned short* __restrict__ A,
                                                    const unsigned short* __restrict__ BT,
                                                    const float* __restrict__ bias,
                                                    void* __restrict__ Cout,
                                                    int M, int N) {
    constexpr int K  = 512;
    constexpr int KH = 256;                 // K-half staged per panel load
    constexpr int BN = 64;
    constexpr int BM = 4 * R * 16;          // 4 waves x R frags x 16 rows = 128
    constexpr int C  = BN / 16;             // 4 n-frags per wave
    __shared__ unsigned short lB[BN * KH];  // 32 KB

    const int t    = threadIdx.x;
    const int lane = t & 63;
    const int wv   = t >> 6;
    const int lm   = lane & 15;
    const int q    = lane >> 4;

    const int MBLK = (M + BM - 1) / BM;
    const int NBN  = N / BN;
    int mblk, nblk;
    {
        const int i    = blockIdx.x;
        const int full = (MBLK / 8) * 8 * NBN;
        if (i < full) {
            const int g = i / (8 * NBN);
            const int l = i % (8 * NBN);
            mblk = g * 8 + (l & 7);
            nblk = l >> 3;
        } else {
            const int t2  = i - full;
            const int rem = MBLK & 7;
            mblk = (MBLK / 8) * 8 + t2 % rem;
            nblk = t2 / rem;
        }
    }
    const int m0 = mblk * BM;
    const int n0 = nblk * BN;

    // ---- per-lane A row pointers (clamped for the ragged last m-slab) ----
    const unsigned short* ap[R];
#pragma unroll
    for (int r = 0; r < R; ++r) {
        int gr = m0 + wv * R * 16 + r * 16 + lm;
        if (gr >= M) gr = M - 1;
        ap[r] = A + (size_t)gr * K + q * 8;
    }

    f32x4 acc[R][C] = {};
    bf16x8 aC[R], aN[R];
#pragma unroll
    for (int r = 0; r < R; ++r) aC[r] = *(const bf16x8*)ap[r];   // ks = 0

    for (int half = 0; half < 2; ++half) {
        if (half) __syncthreads();          // all reads of previous half done
        const int kh = half * KH;
        // ---- stage this K-half of the B^T panel (swizzled source) ----
#pragma unroll
        for (int i = 0; i < (BN * (KH / 8)) / 256; ++i) {   // 8 iters
            const int idx = i * 256 + t;
            const int row = idx >> 5;                       // 32 chunks/row
            const int c32 = idx & 31;
            const int g   = (c32 & ~7) | ((c32 & 7) ^ (row & 7));
            gl2lds16(BT + (size_t)(n0 + row) * K + kh + g * 8, &lB[idx * 8]);
        }
        __syncthreads();                    // panel ready (drains vmcnt)

#pragma unroll
        for (int s = 0; s < 8; ++s) {
            const int ks = half * 8 + s;
            if (ks < 15) {
#pragma unroll
                for (int r = 0; r < R; ++r)
                    aN[r] = *(const bf16x8*)(ap[r] + (ks + 1) * 32);  // 1-deep
            }
            bf16x8 bf[C];
#pragma unroll
            for (int c = 0; c < C; ++c) {
                const int row  = c * 16 + lm;
                const int c32  = s * 4 + q;
                const int phys = (c32 & ~7) | ((c32 & 7) ^ (row & 7));
                bf[c] = *(const bf16x8*)&lB[row * KH + phys * 8];
            }
#pragma unroll
            for (int r = 0; r < R; ++r)
#pragma unroll
                for (int c = 0; c < C; ++c)
                    acc[r][c] = __builtin_amdgcn_mfma_f32_16x16x32_bf16(
                        aC[r], bf[c], acc[r][c], 0, 0, 0);
#pragma unroll
            for (int r = 0; r < R; ++r) aC[r] = aN[r];
        }
    }

    // epilogue: C/D layout col=lane&15, row=quad*4+reg
#pragma unroll
    for (int r = 0; r < R; ++r) {
#pragma unroll
        for (int c = 0; c < C; ++c) {
            const int colg = n0 + c * 16 + lm;
            const float bb = HASBIAS ? bias[colg] : 0.0f;
            const int rowb = m0 + wv * R * 16 + r * 16 + q * 4;
#pragma unroll
            for (int i = 0; i < 4; ++i) {
                const int rr = rowb + i;
                if (rr < M) {
                    float v = acc[r][c][i] + bb;
                    if (RELU) v = fmaxf(v, 0.0f);
                    if (OUTBF16)
                        ((unsigned short*)Cout)[(size_t)rr * N + colg] = f2bf(v);
                    else
                        ((float*)Cout)[(size_t)rr * N + colg] = v;
                }
            }
        }
    }
}

// ================= CSR-pull aggregation =================
__global__ __launch_bounds__(256) void gcn_aggregate(const unsigned short* __restrict__ hW,
                                                     const int* __restrict__ row_ptr,
                                                     const int2* __restrict__ ew,
                                                     const float* __restrict__ dinv,
                                                     const float* __restrict__ bias,
                                                     unsigned short* __restrict__ out) {
    const int wv   = threadIdx.x >> 6;
    const int lane = threadIdx.x & 63;
    int d = blockIdx.x * 4 + wv;
    d = __builtin_amdgcn_readfirstlane(d);
    if (d >= N_NODES) return;
    const int beg = __builtin_amdgcn_readfirstlane(row_ptr[d]);
    const int end = __builtin_amdgcn_readfirstlane(row_ptr[d + 1]);
    const size_t foff = (size_t)lane * 8;

    const float di = dinv[d];
    const float sl = di * di;
    u16x8 sv = *(const u16x8*)(hW + (size_t)d * NHID + foff);
    float acc[8];
#pragma unroll
    for (int i = 0; i < 8; ++i) acc[i] = bf2f(sv[i]) * sl;

    for (int j = beg; j < end; j += 8) {
        int   sK[8];
        float wK[8];
        u16x8 v[8];
#pragma unroll
        for (int k = 0; k < 8; ++k) {
            const int jj = j + k;            // may overrun into pad (safe)
            const int2 e = ew[jj];
            const bool valid = jj < end;     // wave-uniform
            sK[k] = valid ? e.x : 0;
            wK[k] = valid ? __int_as_float(e.y) : 0.0f;
        }
#pragma unroll
        for (int k = 0; k < 8; ++k)
            v[k] = *(const u16x8*)(hW + (size_t)sK[k] * NHID + foff);
#pragma unroll
        for (int k = 0; k < 8; ++k)
#pragma unroll
            for (int i = 0; i < 8; ++i)
                acc[i] += bf2f(v[k][i]) * wK[k];
    }

    const float4 b0v = *(const float4*)(bias + foff);
    const float4 b1v = *(const float4*)(bias + foff + 4);
    u16x8 r;
    r[0] = f2bf(fmaxf(acc[0] + b0v.x, 0.0f));
    r[1] = f2bf(fmaxf(acc[1] + b0v.y, 0.0f));
    r[2] = f2bf(fmaxf(acc[2] + b0v.z, 0.0f));
    r[3] = f2bf(fmaxf(acc[3] + b0v.w, 0.0f));
    r[4] = f2bf(fmaxf(acc[4] + b1v.x, 0.0f));
    r[5] = f2bf(fmaxf(acc[5] + b1v.y, 0.0f));
    r[6] = f2bf(fmaxf(acc[6] + b1v.z, 0.0f));
    r[7] = f2bf(fmaxf(acc[7] + b1v.w, 0.0f));
    *(u16x8*)(out + (size_t)d * NHID + foff) = r;
}

// ================= launch =================
extern "C" void kernel_launch(void* const* d_in, const int* in_sizes, int n_in,
                              void* d_out, int out_size, void* d_ws, size_t ws_size,
                              hipStream_t stream) {
    const float* x       = (const float*)d_in[0];
    const int*   ei      = (const int*)d_in[1];
    const float* W_enc   = (const float*)d_in[2];
    const float* b_enc   = (const float*)d_in[3];
    const float* W_convs = (const float*)d_in[4];
    const float* b_convs = (const float*)d_in[5];
    const float* W_dec   = (const float*)d_in[6];
    const float* b_dec   = (const float*)d_in[7];
    float* out = (float*)d_out;

    const int* src = ei;
    const int* dst = ei + E_EDGES;

    char* ws = (char*)d_ws;
    auto alloc = [&](size_t bytes) {
        char* p = ws;
        ws += (bytes + 255) / 256 * 256;
        return p;
    };
    float* dinv     = (float*)alloc(N_NODES * 4);
    int*   counts   = (int*)  alloc((N_NODES + NBLK) * 4);   // bsums adjacent
    int*   bsums    = counts + N_NODES;
    int*   row_ptr  = (int*)  alloc((N_NODES + 1) * 4);
    int*   cursor   = (int*)  alloc(N_NODES * 4);
    int2*  ew       = (int2*) alloc((E_EDGES + 8) * 8);
    unsigned short* WencT = (unsigned short*)alloc((size_t)NFEAT * NHID * 2);
    unsigned short* WcvT  = (unsigned short*)alloc((size_t)NLAYERS * NHID * NHID * 2);
    unsigned short* WdecT = (unsigned short*)alloc((size_t)NHID * NCLASS * 2);
    unsigned short* B1    = (unsigned short*)alloc((size_t)N_NODES * NHID * 2);
    unsigned short* B2    = (unsigned short*)alloc((size_t)N_NODES * NHID * 2);
    unsigned short* Xbf   = B2;   // x-bf16 scratch: dead once encoder GEMM ran

    // ---- CSR build + weight conversion + x conversion (fused) ----
    hipMemsetAsync(counts, 0, (N_NODES + NBLK) * sizeof(int), stream);
    prep_all<<<CNT_BLOCKS + 6 * 256 + CVT_BLOCKS, 256, 0, stream>>>(
        dst, counts, bsums, W_enc, W_convs, W_dec, WencT, WcvT, WdecT, x, Xbf);
    write_rowptr<<<NBLK, 256, 0, stream>>>(counts, bsums, row_ptr, cursor, dinv);
    csr_fill<<<(E_EDGES + 255) / 256, 256, 0, stream>>>(src, dst, dinv, cursor, ew);

    // BM=128: MBLK=157; BN=64: NBN=8 hidden, 1 classes
    const int MBLK128 = (N_NODES + 127) / 128;   // 157

    // ---- encoder: bf16 x from prep ----
    gemm_bres<2, true, true, true>
        <<<MBLK128 * (NHID / 64), 256, 0, stream>>>(
        Xbf, WencT, b_enc, B1, N_NODES, NHID);

    // ---- conv layers ----
    for (int L = 0; L < NLAYERS; ++L) {
        gemm_bres<2, false, false, true>
            <<<MBLK128 * (NHID / 64), 256, 0, stream>>>(
            B1, WcvT + (size_t)L * NHID * NHID, nullptr, B2, N_NODES, NHID);
        gcn_aggregate<<<(N_NODES + 3) / 4, 256, 0, stream>>>(
            B2, row_ptr, ew, dinv, b_convs + (size_t)L * NHID, B1);
    }

    // ---- decoder: single n-block ----
    gemm_bres<2, false, true, false>
        <<<MBLK128 * (NCLASS / 64), 256, 0, stream>>>(
        B1, WdecT, b_dec, out, N_NODES, NCLASS);
}

// Round 7
// 343.841 us; speedup vs baseline: 11.3325x; 1.1569x over previous
//
#include <hip/hip_runtime.h>

#define N_NODES 20000
#define E_EDGES 160000
#define NFEAT   512
#define NHID    512
#define NCLASS  64
#define NLAYERS 4

#define SCAN_CHUNK 1024
#define NBLK ((N_NODES + SCAN_CHUNK - 1) / SCAN_CHUNK)   // 20
#define CNT_BLOCKS ((E_EDGES + 255) / 256)               // 625
#define CVT_BLOCKS ((N_NODES * NFEAT) / 2048)            // 5000 (8 floats/thread)

using bf16x8 = __attribute__((ext_vector_type(8))) short;          // MFMA A/B frag
using f32x4  = __attribute__((ext_vector_type(4))) float;          // MFMA C/D frag
using u16x8  = __attribute__((ext_vector_type(8))) unsigned short; // 16B bf16 vector

__device__ __forceinline__ unsigned short f2bf(float f) {
    union { float f; unsigned int u; } v; v.f = f;
    unsigned int u = v.u + 0x7FFFu + ((v.u >> 16) & 1u);   // RNE
    return (unsigned short)(u >> 16);
}
__device__ __forceinline__ float bf2f(unsigned short h) {
    union { unsigned int u; float f; } v; v.u = ((unsigned int)h) << 16;
    return v.f;
}
__device__ __forceinline__ void gl2lds16(const void* gptr, void* lptr) {
    __builtin_amdgcn_global_load_lds(
        (const __attribute__((address_space(1))) unsigned int*)gptr,
        (__attribute__((address_space(3))) unsigned int*)lptr,
        16, 0, 0);
}

// ==== fused prep: edge counting + weight transposes + x fp32->bf16 convert ====
__global__ __launch_bounds__(256) void prep_all(const int* __restrict__ dst,
                                                int* __restrict__ counts,
                                                int* __restrict__ bsums,
                                                const float* __restrict__ W_enc,
                                                const float* __restrict__ W_convs,
                                                const float* __restrict__ W_dec,
                                                unsigned short* __restrict__ WencT,
                                                unsigned short* __restrict__ WcvT,
                                                unsigned short* __restrict__ WdecT,
                                                const float* __restrict__ x,
                                                unsigned short* __restrict__ Xbf) {
    __shared__ int bins[NBLK];
    __shared__ float tile[32][33];
    const int b = blockIdx.x, t = threadIdx.x;

    if (b < CNT_BLOCKS) {
        if (t < NBLK) bins[t] = 0;
        __syncthreads();
        const int e = b * 256 + t;
        if (e < E_EDGES) {
            const int d = dst[e];
            atomicAdd(&counts[d], 1);
            atomicAdd(&bins[d >> 10], 1);         // SCAN_CHUNK = 1024
        }
        __syncthreads();
        if (t < NBLK && bins[t]) atomicAdd(&bsums[t], bins[t]);
        return;
    }

    if (b >= CNT_BLOCKS + 6 * 256) {
        // ---- convert x -> bf16 (into B2 scratch; dead after encoder GEMM) ----
        const int cid = b - CNT_BLOCKS - 6 * 256;
        const size_t base = (size_t)cid * 2048 + (size_t)t * 8;
        const float4 f0 = *(const float4*)(x + base);
        const float4 f1 = *(const float4*)(x + base + 4);
        u16x8 pk;
        pk[0] = f2bf(f0.x); pk[1] = f2bf(f0.y);
        pk[2] = f2bf(f0.z); pk[3] = f2bf(f0.w);
        pk[4] = f2bf(f1.x); pk[5] = f2bf(f1.y);
        pk[6] = f2bf(f1.z); pk[7] = f2bf(f1.w);
        *(u16x8*)(Xbf + base) = pk;
        return;
    }

    // ---- transpose role ----
    const int bid = b - CNT_BLOCKS;
    const int id  = bid >> 8;            // matrix 0..5
    const int rem = bid & 255;
    const int n0  = (rem & 15) * 32;
    const int k0  = (rem >> 4) * 32;
    const float* W; unsigned short* WT; int N;
    const int K = 512;
    if (id == 0)            { W = W_enc; WT = WencT; N = NHID; }
    else if (id <= NLAYERS) { W = W_convs + (size_t)(id - 1) * NHID * NHID;
                              WT = WcvT  + (size_t)(id - 1) * NHID * NHID; N = NHID; }
    else                    { W = W_dec; WT = WdecT; N = NCLASS; }
    if (n0 >= N) return;
    const int tx = t & 31, ty = t >> 5;
#pragma unroll
    for (int i = 0; i < 32; i += 8)
        tile[ty + i][tx] = W[(size_t)(k0 + ty + i) * N + n0 + tx];
    __syncthreads();
#pragma unroll
    for (int i = 0; i < 32; i += 8)
        WT[(size_t)(n0 + ty + i) * K + k0 + tx] = f2bf(tile[tx][ty + i]);
}

// row_ptr + cursor + dinv in one pass; bsums-prefix fused in (wave 0 reduces)
__global__ __launch_bounds__(256) void write_rowptr(const int* __restrict__ counts,
                                                    const int* __restrict__ bsums,
                                                    int* __restrict__ row_ptr,
                                                    int* __restrict__ cursor,
                                                    float* __restrict__ dinv) {
    __shared__ int part[256];
    __shared__ int boff_s;
    const int b = blockIdx.x, t = threadIdx.x;

    if (t < 64) {               // wave 0: boff_s = sum of bsums[0..b-1]
        int v = (t < NBLK && t < b) ? bsums[t] : 0;
        for (int off = 32; off > 0; off >>= 1) v += __shfl_xor(v, off, 64);
        if (t == 0) boff_s = v;
    }

    const int base = b * SCAN_CHUNK + t * 4;
    int c[4], s = 0;
    for (int i = 0; i < 4; ++i) {
        int idx = base + i;
        c[i] = (idx < N_NODES) ? counts[idx] : 0;
        s += c[i];
    }
    part[t] = s;
    __syncthreads();
    for (int off = 1; off < 256; off <<= 1) {
        int v = (t >= off) ? part[t - off] : 0;
        __syncthreads();
        part[t] += v;
        __syncthreads();
    }
    int run = boff_s + ((t == 0) ? 0 : part[t - 1]);
    for (int i = 0; i < 4; ++i) {
        int idx = base + i;
        if (idx < N_NODES) {
            row_ptr[idx] = run;
            cursor[idx]  = run;
            dinv[idx]    = rsqrtf((float)c[i] + 1.0f);
            run += c[i];
        }
    }
    if (b == 0 && t == 0) row_ptr[N_NODES] = E_EDGES;
}

// fill packed (col, wgt) pairs; pad 8 entries past E with {node 0, weight 0}
__global__ __launch_bounds__(256) void csr_fill(const int* __restrict__ src,
                                                const int* __restrict__ dst,
                                                const float* __restrict__ dinv,
                                                int* __restrict__ cursor,
                                                int2* __restrict__ ew) {
    int e = blockIdx.x * 256 + threadIdx.x;
    if (e < E_EDGES) {
        int s = src[e], d = dst[e];
        int pos = atomicAdd(&cursor[d], 1);
        ew[pos] = make_int2(s, __float_as_int(dinv[s] * dinv[d]));
    }
    if (e < 8) ew[E_EDGES + e] = make_int2(0, 0);
}

// ================= bf16 MFMA GEMM (R1-proven: dbuf + counted vmcnt) ========
// C[M,N] = A[M,K] @ B[K,N]; A bf16 row-major, BT = B^T bf16 [N][K]. BK=32,
// 256 threads = 4 waves WR x WC; per-wave frag grid R x C.
// K-loop: double-buffered LDS; issue stage(kt+1) BEFORE computing kt, wait
// with counted s_waitcnt vmcnt(LPT) + RAW s_barrier (no __syncthreads drain).
// Rule 18: sched_barrier(0) after every inline-asm waitcnt.
// XCD swizzle: same-m n-blocks land on same XCD -> A-slab L2 reuse.
template <int BM, int BN, int WR, int WC, bool RELU, bool HASBIAS, bool OUTBF16>
__global__ __launch_bounds__(256) void gemm_mfma(const unsigned short* __restrict__ A,
                                                 const unsigned short* __restrict__ BT,
                                                 const float* __restrict__ bias,
                                                 void* __restrict__ Cout,
                                                 int M, int N, int K) {
    constexpr int BK  = 32;
    constexpr int R   = BM / (16 * WR);
    constexpr int C   = BN / (16 * WC);
    constexpr int RA  = (BM * BK) / (256 * 8);   // A gl2lds per thread per step
    constexpr int RB  = (BN * BK) / (256 * 8);   // B gl2lds per thread per step
    constexpr int LPT = RA + RB;                 // loads in flight per stage
    __shared__ unsigned short lA[2][BM * BK];
    __shared__ unsigned short lB[2][BN * BK];

    const int t    = threadIdx.x;
    const int lane = t & 63;
    const int wv   = t >> 6;
    const int wr   = wv / WC;
    const int wc   = wv % WC;
    const int lm   = lane & 15;
    const int quad = lane >> 4;

    const int MBLK = (M + BM - 1) / BM;
    const int NBN  = N / BN;
    int mblk, nblk;
    {
        const int i    = blockIdx.x;
        const int full = (MBLK / 8) * 8 * NBN;
        if (i < full) {
            const int g = i / (8 * NBN);
            const int l = i % (8 * NBN);
            mblk = g * 8 + (l & 7);
            nblk = l >> 3;
        } else {
            const int t2  = i - full;
            const int rem = MBLK - (MBLK / 8) * 8;
            mblk = (MBLK / 8) * 8 + t2 % rem;
            nblk = t2 / rem;
        }
    }
    const int m0 = mblk * BM;
    const int n0 = nblk * BN;

    f32x4 acc[R][C] = {};

    auto stage = [&](int s, int kt) {
#pragma unroll
        for (int i = 0; i < RA; ++i) {
            int idx = i * 256 + t;
            int row = idx >> 2;              // BK=32 -> 4 x 16B chunks per row
            int kof = (idx & 3) << 3;
            int gr = m0 + row; if (gr >= M) gr = M - 1;
            gl2lds16(A + (size_t)gr * K + kt + kof, &lA[s][idx * 8]);
        }
#pragma unroll
        for (int i = 0; i < RB; ++i) {
            int idx = i * 256 + t;
            int row = idx >> 2;
            int kof = (idx & 3) << 3;
            gl2lds16(BT + (size_t)(n0 + row) * K + kt + kof, &lB[s][idx * 8]);
        }
    };

    stage(0, 0);
    int cur = 0;
    for (int kt = 0; kt < K; kt += BK) {
        if (kt + BK < K) {
            stage(cur ^ 1, kt + BK);         // LPT more loads in flight
            asm volatile("s_waitcnt vmcnt(%0)" :: "i"(LPT) : "memory");
        } else {
            asm volatile("s_waitcnt vmcnt(0)" ::: "memory");
        }
        __builtin_amdgcn_sched_barrier(0);
        __builtin_amdgcn_s_barrier();        // all waves: tile kt landed in LDS

        bf16x8 af[R], bfr[C];
#pragma unroll
        for (int r = 0; r < R; ++r)
            af[r] = *(const bf16x8*)&lA[cur][(wr * R * 16 + r * 16 + lm) * BK + quad * 8];
#pragma unroll
        for (int c = 0; c < C; ++c)
            bfr[c] = *(const bf16x8*)&lB[cur][(wc * C * 16 + c * 16 + lm) * BK + quad * 8];
        asm volatile("s_waitcnt lgkmcnt(0)" ::: "memory");
        __builtin_amdgcn_sched_barrier(0);
#pragma unroll
        for (int r = 0; r < R; ++r)
#pragma unroll
            for (int c = 0; c < C; ++c)
                acc[r][c] = __builtin_amdgcn_mfma_f32_16x16x32_bf16(af[r], bfr[c],
                                                                    acc[r][c], 0, 0, 0);
        __builtin_amdgcn_sched_barrier(0);
        __builtin_amdgcn_s_barrier();        // reads done -> buf[cur] reusable
        cur ^= 1;
    }

    // epilogue: C/D layout col=lane&15, row=quad*4+reg
#pragma unroll
    for (int r = 0; r < R; ++r) {
#pragma unroll
        for (int c = 0; c < C; ++c) {
            const int colg = n0 + wc * C * 16 + c * 16 + lm;
            const float bb = HASBIAS ? bias[colg] : 0.0f;
            const int rowb = m0 + wr * R * 16 + r * 16 + quad * 4;
#pragma unroll
            for (int i = 0; i < 4; ++i) {
                const int rr = rowb + i;
                if (rr < M) {
                    float v = acc[r][c][i] + bb;
                    if (RELU) v = fmaxf(v, 0.0f);
                    if (OUTBF16)
                        ((unsigned short*)Cout)[(size_t)rr * N + colg] = f2bf(v);
                    else
                        ((float*)Cout)[(size_t)rr * N + colg] = v;
                }
            }
        }
    }
}

// ============ CSR-pull aggregation: 2 waves per node (feature split) ========
// R7 change: one node was one wave (64 lanes x 8 feats) -> serial gather chain
// ~1500 cyc with only ~deg/8 rounds to pipeline = latency-bound. Now each node
// is TWO waves, each owning 256 features (64 lanes x 4 feats, u16x4 = 8B/lane,
// 512 B/row/wave still fully coalesced). Halves the per-wave latency chain and
// doubles the number of independent gather streams chip-wide (40000 waves).
// Numerics: identical FP sequence per feature -> bit-identical output.
__global__ __launch_bounds__(256) void gcn_aggregate(const unsigned short* __restrict__ hW,
                                                     const int* __restrict__ row_ptr,
                                                     const int2* __restrict__ ew,
                                                     const float* __restrict__ dinv,
                                                     const float* __restrict__ bias,
                                                     unsigned short* __restrict__ out) {
    const int wv   = threadIdx.x >> 6;           // 0..3
    const int lane = threadIdx.x & 63;
    int d = blockIdx.x * 2 + (wv >> 1);          // 2 nodes per block
    d = __builtin_amdgcn_readfirstlane(d);
    if (d >= N_NODES) return;
    const int fh = wv & 1;                       // feature half 0/1
    const int beg = __builtin_amdgcn_readfirstlane(row_ptr[d]);
    const int end = __builtin_amdgcn_readfirstlane(row_ptr[d + 1]);
    const size_t foff = (size_t)fh * 256 + (size_t)lane * 4;

    const float di = dinv[d];
    const float sl = di * di;
    const ushort4 sv = *(const ushort4*)(hW + (size_t)d * NHID + foff);
    float acc[4];
    acc[0] = bf2f(sv.x) * sl;
    acc[1] = bf2f(sv.y) * sl;
    acc[2] = bf2f(sv.z) * sl;
    acc[3] = bf2f(sv.w) * sl;

    for (int j = beg; j < end; j += 8) {
        int    sK[8];
        float  wK[8];
        ushort4 v[8];
#pragma unroll
        for (int k = 0; k < 8; ++k) {
            const int jj = j + k;            // may overrun into pad (safe)
            const int2 e = ew[jj];
            const bool valid = jj < end;     // wave-uniform
            sK[k] = valid ? e.x : 0;
            wK[k] = valid ? __int_as_float(e.y) : 0.0f;
        }
#pragma unroll
        for (int k = 0; k < 8; ++k)
            v[k] = *(const ushort4*)(hW + (size_t)sK[k] * NHID + foff);
#pragma unroll
        for (int k = 0; k < 8; ++k) {
            acc[0] += bf2f(v[k].x) * wK[k];
            acc[1] += bf2f(v[k].y) * wK[k];
            acc[2] += bf2f(v[k].z) * wK[k];
            acc[3] += bf2f(v[k].w) * wK[k];
        }
    }

    const float4 bv = *(const float4*)(bias + foff);
    ushort4 r;
    r.x = f2bf(fmaxf(acc[0] + bv.x, 0.0f));
    r.y = f2bf(fmaxf(acc[1] + bv.y, 0.0f));
    r.z = f2bf(fmaxf(acc[2] + bv.z, 0.0f));
    r.w = f2bf(fmaxf(acc[3] + bv.w, 0.0f));
    *(ushort4*)(out + (size_t)d * NHID + foff) = r;
}

// ================= launch =================
extern "C" void kernel_launch(void* const* d_in, const int* in_sizes, int n_in,
                              void* d_out, int out_size, void* d_ws, size_t ws_size,
                              hipStream_t stream) {
    const float* x       = (const float*)d_in[0];
    const int*   ei      = (const int*)d_in[1];
    const float* W_enc   = (const float*)d_in[2];
    const float* b_enc   = (const float*)d_in[3];
    const float* W_convs = (const float*)d_in[4];
    const float* b_convs = (const float*)d_in[5];
    const float* W_dec   = (const float*)d_in[6];
    const float* b_dec   = (const float*)d_in[7];
    float* out = (float*)d_out;

    const int* src = ei;
    const int* dst = ei + E_EDGES;

    char* ws = (char*)d_ws;
    auto alloc = [&](size_t bytes) {
        char* p = ws;
        ws += (bytes + 255) / 256 * 256;
        return p;
    };
    float* dinv     = (float*)alloc(N_NODES * 4);
    int*   counts   = (int*)  alloc((N_NODES + NBLK) * 4);   // bsums adjacent
    int*   bsums    = counts + N_NODES;
    int*   row_ptr  = (int*)  alloc((N_NODES + 1) * 4);
    int*   cursor   = (int*)  alloc(N_NODES * 4);
    int2*  ew       = (int2*) alloc((E_EDGES + 8) * 8);
    unsigned short* WencT = (unsigned short*)alloc((size_t)NFEAT * NHID * 2);
    unsigned short* WcvT  = (unsigned short*)alloc((size_t)NLAYERS * NHID * NHID * 2);
    unsigned short* WdecT = (unsigned short*)alloc((size_t)NHID * NCLASS * 2);
    unsigned short* B1    = (unsigned short*)alloc((size_t)N_NODES * NHID * 2);
    unsigned short* B2    = (unsigned short*)alloc((size_t)N_NODES * NHID * 2);
    unsigned short* Xbf   = B2;   // x-bf16 scratch: dead once encoder GEMM ran

    // ---- CSR build + weight conversion + x conversion (fused) ----
    hipMemsetAsync(counts, 0, (N_NODES + NBLK) * sizeof(int), stream);
    prep_all<<<CNT_BLOCKS + 6 * 256 + CVT_BLOCKS, 256, 0, stream>>>(
        dst, counts, bsums, W_enc, W_convs, W_dec, WencT, WcvT, WdecT, x, Xbf);
    write_rowptr<<<NBLK, 256, 0, stream>>>(counts, bsums, row_ptr, cursor, dinv);
    csr_fill<<<(E_EDGES + 255) / 256, 256, 0, stream>>>(src, dst, dinv, cursor, ew);

    const int MBLK64 = (N_NODES + 63) / 64;   // 313

    // ---- encoder (bf16 x from prep): 64x128 tile ----
    gemm_mfma<64, 128, 2, 2, true, true, true>
        <<<MBLK64 * (NHID / 128), 256, 0, stream>>>(
        Xbf, WencT, b_enc, B1, N_NODES, NHID, NFEAT);

    // ---- conv layers ----
    for (int L = 0; L < NLAYERS; ++L) {
        gemm_mfma<64, 128, 2, 2, false, false, true>
            <<<MBLK64 * (NHID / 128), 256, 0, stream>>>(
            B1, WcvT + (size_t)L * NHID * NHID, nullptr, B2, N_NODES, NHID, NHID);
        gcn_aggregate<<<(N_NODES + 1) / 2, 256, 0, stream>>>(
            B2, row_ptr, ew, dinv, b_convs + (size_t)L * NHID, B1);
    }

    // ---- decoder: 64x64 tile ----
    gemm_mfma<64, 64, 2, 2, false, true, false>
        <<<MBLK64 * (NCLASS / 64), 256, 0, stream>>>(
        B1, WdecT, b_dec, out, N_NODES, NCLASS, NHID);
}